// Round 2
// baseline (1430.932 us; speedup 1.0000x reference)
//
#include <hip/hip_runtime.h>
#include <math.h>

#define VOCAB 50000
#define EE 301
#define KP 304     // padded K (multiple of 16; rows EE..KP-1 are zeros)
#define DD 25
#define SEQ 128
#define NC 5
#define BROW 768   // Bmat cols (scan-order, zero-padded): col i*28+j = A[i][e][j] (j<25), i*28+25 = W[e][i]
#define NUSE 700
#define TROW 704   // T row stride (floats); scan reads i*28 .. i*28+27
#define EMT 50112  // embT row stride (padded so 160-wide m-tiles stay in bounds: 313*160=50080<=50112)
#define TM 160     // gemm m-tile
#define MTILES 313 // ceil(50000/160)
#define NTILES (MTILES*3)
#define GEMM_GRID 512  // 2 blocks/CU * 256 CU -> zero-ish tail: 939/1024 = 91.7%

// async global->LDS DMA, 16B per lane, lane i lands at ldsbase + i*16
#define GLOAD_LDS16(g, l) __builtin_amdgcn_global_load_lds( \
    (const __attribute__((address_space(1))) void*)(g),     \
    (__attribute__((address_space(3))) void*)(l), 16, 0, 0)

// ---------------- Bmat[e][c'] in scan order; rows EE..KP-1 zero ----------------
__global__ __launch_bounds__(256) void build_B(
    const float* __restrict__ A, const float* __restrict__ W,
    float* __restrict__ Bmat)
{
    int e = blockIdx.x;
    for (int c = threadIdx.x; c < BROW; c += 256) {
        float v = 0.f;
        if (e < EE && c < NUSE) {
            int i = c / 28, j = c % 28;
            if (j < 25)       v = A[((size_t)i * EE + e) * DD + j];
            else if (j == 25) v = W[(size_t)e * DD + i];
        }
        Bmat[(size_t)e * BROW + c] = v;
    }
}

// ---------------- embT[k][m] = emb[m][k] (pure copy; zeros for k>=EE, m>=VOCAB) ----------------
__global__ __launch_bounds__(256) void transpose_emb(
    const float* __restrict__ emb, float* __restrict__ embT)
{
    __shared__ float t[64][65];
    int m0 = blockIdx.x * 64, k0 = blockIdx.y * 64;
    int tx = threadIdx.x & 63, ty = threadIdx.x >> 6;   // ty 0..3
#pragma unroll
    for (int it = 0; it < 16; ++it) {
        int m = m0 + ty * 16 + it;
        int k = k0 + tx;
        t[tx][ty * 16 + it] = (m < VOCAB && k < EE) ? emb[(size_t)m * EE + k] : 0.f;
    }
    __syncthreads();
#pragma unroll
    for (int it = 0; it < 16; ++it) {
        int kl = ty * 16 + it;
        int k = k0 + kl;
        if (k < KP) embT[(size_t)k * EMT + m0 + tx] = t[kl][tx];
    }
}

// ---------------- GEMM v5: persistent grid, 160m x 256n tile, 10x16 microtile ----------------
// Same bit-exact ascending-k fmaf chain per output element as v3 (k 0..303, zero tail).
// Tail fix: 939 tiles over exactly 512 resident blocks (2/CU) -> 2 rounds, 91.7% eff
// (was 1173 tiles / 512 slots -> 3 rounds, 76.4%).
__global__ __launch_bounds__(256, 2) void gemm_T5(
    const float* __restrict__ embT,  // [KP][EMT] k-major
    const float* __restrict__ Bmat,  // [KP][BROW]
    float* __restrict__ T)           // [VOCAB][TROW]
{
    __shared__ float As[2][16 * TM];   // 2 x 10240 B (flat [16][160])
    __shared__ float Bs[2][16][256];   // 2 x 16384 B
    int tid = threadIdx.x;
    int tx = tid & 15, ty = tid >> 4;
    int wave = tid >> 6, lane = tid & 63;

    // As DMA plan: 16*160 floats = 10 instrs of 1024B. wave w issues t = j*4+w (t<10).
    // float index f = t*256 + lane*4 -> row kk=f/160, col=f%160 (never crosses a row: f%4==0).
    int aoff[3], alds[3]; bool aval[3];
#pragma unroll
    for (int j = 0; j < 3; ++j) {
        int t = j * 4 + wave;
        aval[j] = (t < 10);
        int f = (t < 10 ? t : 0) * 256 + lane * 4;
        int kk = f / TM;
        int col = f - kk * TM;
        aoff[j] = kk * EMT + col;
        alds[j] = (t < 10 ? t : 0) * 1024;
    }

    for (int tix = blockIdx.x; tix < NTILES; tix += gridDim.x) {
        int mi = tix / 3, ni = tix - mi * 3;
        int m0 = mi * TM, n0 = ni * 256;

        float acc[10][16];
#pragma unroll
        for (int a = 0; a < 10; ++a)
#pragma unroll
            for (int c = 0; c < 16; ++c) acc[a][c] = 0.f;

        auto dma_tile = [&](int k0, int buf) {
#pragma unroll
            for (int j = 0; j < 3; ++j)
                if (aval[j])
                    GLOAD_LDS16(embT + (size_t)k0 * EMT + m0 + aoff[j],
                                (char*)&As[buf][0] + alds[j]);
#pragma unroll
            for (int j = 0; j < 4; ++j) {
                int r = wave * 4 + j;
                GLOAD_LDS16(Bmat + (size_t)(k0 + r) * BROW + n0 + lane * 4,
                            &Bs[buf][r][0]);
            }
        };

        dma_tile(0, 0);
        __syncthreads();

        int buf = 0;
        for (int k0 = 0; k0 < KP; k0 += 16) {
            if (k0 + 16 < KP) dma_tile(k0 + 16, buf ^ 1);
#pragma unroll
            for (int kk = 0; kk < 16; ++kk) {  // global k strictly ascending
                const float* Ar = &As[buf][kk * TM];
                float4 a0 = *(const float4*)&Ar[ty * 4];
                float4 a1 = *(const float4*)&Ar[64 + ty * 4];
                float2 a2 = *(const float2*)&Ar[128 + ty * 2];
                float4 b0 = *(const float4*)&Bs[buf][kk][tx * 4];
                float4 b1 = *(const float4*)&Bs[buf][kk][64 + tx * 4];
                float4 b2 = *(const float4*)&Bs[buf][kk][128 + tx * 4];
                float4 b3 = *(const float4*)&Bs[buf][kk][192 + tx * 4];
                float av[10] = {a0.x, a0.y, a0.z, a0.w, a1.x, a1.y, a1.z, a1.w,
                                a2.x, a2.y};
                float bv[16] = {b0.x, b0.y, b0.z, b0.w, b1.x, b1.y, b1.z, b1.w,
                                b2.x, b2.y, b2.z, b2.w, b3.x, b3.y, b3.z, b3.w};
#pragma unroll
                for (int a = 0; a < 10; ++a)
#pragma unroll
                    for (int c = 0; c < 16; ++c)
                        acc[a][c] = fmaf(av[a], bv[c], acc[a][c]);
            }
            __syncthreads();
            buf ^= 1;
        }

        // epilogue: coalesced float4 stores (layout already scan-order)
#pragma unroll
        for (int a = 0; a < 10; ++a) {
            int mo = (a < 4) ? (ty * 4 + a)
                   : (a < 8) ? (64 + ty * 4 + (a - 4))
                             : (128 + ty * 2 + (a - 8));
            int m = m0 + mo;
            if (m < VOCAB) {
                float* row = T + (size_t)m * TROW;
#pragma unroll
                for (int gc = 0; gc < 4; ++gc) {
                    int n = n0 + gc * 64 + tx * 4;
                    if (n < TROW) {
                        int c = gc * 4;
                        *(float4*)(row + n) = make_float4(
                            acc[a][c], acc[a][c + 1], acc[a][c + 2], acc[a][c + 3]);
                    }
                }
            }
        }
        // no extra barrier needed: last LDS reads were fenced by the final
        // in-loop __syncthreads(); epilogue touches only registers/global.
    }
}

// ---------------- fallback GEMM (R11): register-prefetch pipeline ----------------
__global__ __launch_bounds__(256, 2) void gemm_T(
    const float* __restrict__ emb, const float* __restrict__ Bmat,
    float* __restrict__ T)
{
    __shared__ float As[2][16][132];
    __shared__ float Bs[2][16][132];
    int tid = threadIdx.x;
    int tx = tid & 15, ty = tid >> 4;
    int m0 = blockIdx.x * 128, n0 = blockIdx.y * 128;
    float acc[8][8];
#pragma unroll
    for (int a = 0; a < 8; ++a)
#pragma unroll
        for (int c = 0; c < 8; ++c) acc[a][c] = 0.f;
    float ar[8]; float4 br[2];
    int kl0 = tid >> 5, nl0 = (tid & 31) * 4;
#pragma unroll
    for (int it = 0; it < 8; ++it) {
        int m = m0 + ty + 16 * it, k = tx;
        ar[it] = (m < VOCAB && k < EE) ? emb[(size_t)m * EE + k] : 0.f;
    }
#pragma unroll
    for (int it = 0; it < 2; ++it) {
        int k = kl0 + 8 * it;
        br[it] = (k < EE) ? *(const float4*)(Bmat + (size_t)k * BROW + n0 + nl0)
                          : make_float4(0.f, 0.f, 0.f, 0.f);
    }
#pragma unroll
    for (int it = 0; it < 8; ++it) As[0][tx][ty + 16 * it] = ar[it];
#pragma unroll
    for (int it = 0; it < 2; ++it) *(float4*)(&Bs[0][kl0 + 8 * it][nl0]) = br[it];
    __syncthreads();
    int buf = 0;
    for (int k0 = 0; k0 < EE; k0 += 16) {
        int k1 = k0 + 16;
        bool more = (k1 < EE);
        if (more) {
#pragma unroll
            for (int it = 0; it < 8; ++it) {
                int m = m0 + ty + 16 * it, k = k1 + tx;
                ar[it] = (m < VOCAB && k < EE) ? emb[(size_t)m * EE + k] : 0.f;
            }
#pragma unroll
            for (int it = 0; it < 2; ++it) {
                int k = k1 + kl0 + 8 * it;
                br[it] = (k < EE) ? *(const float4*)(Bmat + (size_t)k * BROW + n0 + nl0)
                                  : make_float4(0.f, 0.f, 0.f, 0.f);
            }
        }
#pragma unroll
        for (int kk = 0; kk < 16; ++kk) {
            float4 a0 = *(const float4*)&As[buf][kk][ty * 4];
            float4 a1 = *(const float4*)&As[buf][kk][64 + ty * 4];
            float4 b0 = *(const float4*)&Bs[buf][kk][tx * 4];
            float4 b1 = *(const float4*)&Bs[buf][kk][64 + tx * 4];
            float av[8] = {a0.x, a0.y, a0.z, a0.w, a1.x, a1.y, a1.z, a1.w};
            float bv[8] = {b0.x, b0.y, b0.z, b0.w, b1.x, b1.y, b1.z, b1.w};
#pragma unroll
            for (int a = 0; a < 8; ++a)
#pragma unroll
                for (int c = 0; c < 8; ++c)
                    acc[a][c] = fmaf(av[a], bv[c], acc[a][c]);
        }
        if (more) {
            int nb = buf ^ 1;
#pragma unroll
            for (int it = 0; it < 8; ++it) As[nb][tx][ty + 16 * it] = ar[it];
#pragma unroll
            for (int it = 0; it < 2; ++it) *(float4*)(&Bs[nb][kl0 + 8 * it][nl0]) = br[it];
            __syncthreads();
            buf = nb;
        }
    }
#pragma unroll
    for (int gi = 0; gi < 2; ++gi) {
#pragma unroll
        for (int r = 0; r < 4; ++r) {
            int m = m0 + gi * 64 + ty * 4 + r;
            if (m < VOCAB) {
                float* row = T + (size_t)m * TROW;
#pragma unroll
                for (int gc = 0; gc < 2; ++gc) {
                    int n = n0 + gc * 64 + tx * 4;
                    if (n < TROW) {
                        int a = gi * 4 + r, c = gc * 4;
                        *(float4*)(row + n) = make_float4(
                            acc[a][c], acc[a][c + 1], acc[a][c + 2], acc[a][c + 3]);
                    }
                }
            }
        }
    }
}

// ---------------- scan: frozen numerics, depth-3 prefetch (4 rotating buffers) ----------------
__global__ __launch_bounds__(256, 1) void rnn_scan_np6(
    const int*   __restrict__ words,
    const float* __restrict__ T,
    const float* __restrict__ V,
    const float* __restrict__ bvec,
    const float* __restrict__ outW,
    const float* __restrict__ outB,
    float* __restrict__ out,
    int B)
{
    int tid = threadIdx.x;
    int g = tid >> 5, i = tid & 31;
    int b = blockIdx.x * 8 + g;
    bool act = (i < DD) && (b < B);
    int ii = (i < DD) ? i : (DD - 1);
    int bsafe = (b < B) ? b : 0;
    const int* wr = words + (size_t)bsafe * SEQ;

    float Vcol[DD];
#pragma unroll
    for (int j = 0; j < DD; ++j) Vcol[j] = V[j * DD + ii];
    float bi = bvec[ii];

    float hr[DD];
#pragma unroll
    for (int j = 0; j < DD; ++j) hr[j] = 0.f;
    hr[DD - 1] = 1.f;                // h0 = e_24

    bool sse = ((b & 3) == 0) && ((i & 3) == 0);
    const float* base = T + (size_t)ii * 28;

    float4 A0[7], A1[7], A2[7], A3[7];
    auto LD = [&](float4* dst, int t) {
        const float* R = base + (size_t)wr[t] * TROW;
#pragma unroll
        for (int u = 0; u < 7; ++u) dst[u] = *(const float4*)(R + u * 4);
    };

    float hnew = 0.f;
    auto STEP = [&](const float4* C) {
        float Tj[28];
#pragma unroll
        for (int u = 0; u < 7; ++u) {
            Tj[u * 4 + 0] = C[u].x; Tj[u * 4 + 1] = C[u].y;
            Tj[u * 4 + 2] = C[u].z; Tj[u * 4 + 3] = C[u].w;
        }
        float qv = Tj[25];
        float a;
        if (sse) {
            float p0 = 0.f, p1 = 0.f, p2 = 0.f, p3 = 0.f;
#pragma unroll
            for (int j = 0; j < 24; j += 4) {
                p0 = __fadd_rn(p0, __fmul_rn(Tj[j],     hr[j]));
                p1 = __fadd_rn(p1, __fmul_rn(Tj[j + 1], hr[j + 1]));
                p2 = __fadd_rn(p2, __fmul_rn(Tj[j + 2], hr[j + 2]));
                p3 = __fadd_rn(p3, __fmul_rn(Tj[j + 3], hr[j + 3]));
            }
            float s02 = __fadd_rn(p0, p2);
            float s13 = __fadd_rn(p1, p3);
            a = __fadd_rn(s02, s13);
            a = __fadd_rn(a, __fmul_rn(Tj[24], hr[24]));
        } else {
            a = 0.f;
#pragma unroll
            for (int j = 0; j < DD; ++j)
                a = __fadd_rn(a, __fmul_rn(Tj[j], hr[j]));
        }
        float r2 = 0.f;
#pragma unroll
        for (int j = 0; j < DD; ++j)
            r2 = fmaf(hr[j], Vcol[j], r2);
        float lin = __fadd_rn(__fadd_rn(qv, r2), bi);
        float pre = __fadd_rn(a, lin);
        hnew = act ? (float)tanh((double)pre) : 0.f;
#pragma unroll
        for (int j = 0; j < DD; ++j)
            hr[j] = __shfl(hnew, j, 32);
    };

    LD(A0, 0); LD(A1, 1); LD(A2, 2);
    int t = 0;
    for (; t + 6 < SEQ; t += 4) {            // t = 0,4,...,120
        LD(A3, t + 3); STEP(A0);
        LD(A0, t + 4); STEP(A1);
        LD(A1, t + 5); STEP(A2);
        LD(A2, t + 6); STEP(A3);
    }
    // t == 124: A0<-124, A1<-125, A2<-126 loaded; steps 124..127 remain
    LD(A3, 127);
    STEP(A0); STEP(A1); STEP(A2); STEP(A3);

    if (i < NC && b < B) {
        float acc = 0.f;
#pragma unroll
        for (int j = 0; j < DD; ++j)
            acc = fmaf(hr[j], outW[i * DD + j], acc);
        float l = __fadd_rn(acc, outB[i]);
        out[(size_t)b * NC + i] = (float)(1.0 / (1.0 + exp(-(double)l)));
    }
}

extern "C" void kernel_launch(void* const* d_in, const int* in_sizes, int n_in,
                              void* d_out, int out_size, void* d_ws, size_t ws_size,
                              hipStream_t stream)
{
    const int*   words = (const int*)d_in[0];
    const float* emb   = (const float*)d_in[2];
    const float* A     = (const float*)d_in[3];
    const float* W     = (const float*)d_in[4];
    const float* V     = (const float*)d_in[5];
    const float* bias  = (const float*)d_in[6];
    const float* outW  = (const float*)d_in[7];
    const float* outB  = (const float*)d_in[8];
    float* out = (float*)d_out;
    int B = in_sizes[0] / SEQ;

    const size_t T_OFF    = (size_t)1 << 20;                 // Bmat: 304*768*4 = 0.93 MB
    const size_t EMBT_OFF = (size_t)144 << 20;               // T: 50000*704*4 = 140.8 MB
    const size_t NEED     = EMBT_OFF + (size_t)KP * EMT * 4; // + embT 61.0 MB ≈ 212 MB
    float* Bmat = (float*)d_ws;
    float* T    = (float*)((char*)d_ws + T_OFF);
    float* embT = (float*)((char*)d_ws + EMBT_OFF);

    build_B<<<KP, 256, 0, stream>>>(A, W, Bmat);
    if (ws_size >= NEED) {
        transpose_emb<<<dim3(EMT / 64, (KP + 63) / 64), 256, 0, stream>>>(emb, embT);
        gemm_T5<<<GEMM_GRID, 256, 0, stream>>>(embT, Bmat, T);
    } else {
        gemm_T<<<dim3((VOCAB + 127) / 128, 6), 256, 0, stream>>>(emb, Bmat, T);
    }
    rnn_scan_np6<<<(B + 7) / 8, 256, 0, stream>>>(words, T, V, bias, outW, outB, out, B);
}

// Round 3
// 626.461 us; speedup vs baseline: 2.2842x; 2.2842x over previous
//
#include <hip/hip_runtime.h>
#include <math.h>

#define VOCAB 50000
#define EE 301
#define KP 304     // padded K (multiple of 16; rows EE..KP-1 are zeros)
#define DD 25
#define SEQ 128
#define NC 5
#define BROW 768   // Bmat cols (scan-order, zero-padded): col i*28+j = A[i][e][j] (j<25), i*28+25 = W[e][i]
#define NUSE 700
#define TROW 704   // T row stride (floats); scan reads i*28 .. i*28+27
#define EMT 50112  // embT row stride (zero-padded cols VOCAB..EMT-1)
#define MTILES 391 // ceil(50000/128)
#define NTILES (MTILES*3)   // 1173
#define FULLT 1024          // tiles done as full 128x256 (exactly 2 rounds of 512)
#define SUBT ((NTILES - FULLT) * 2)  // 298 half-width (128x128) tail subtiles
#define GEMM_GRID 512       // 2 blocks/CU * 256 CU

// async global->LDS DMA, 16B per lane, lane i lands at ldsbase + i*16
#define GLOAD_LDS16(g, l) __builtin_amdgcn_global_load_lds( \
    (const __attribute__((address_space(1))) void*)(g),     \
    (__attribute__((address_space(3))) void*)(l), 16, 0, 0)

// ---------------- Bmat[e][c'] in scan order; rows EE..KP-1 zero ----------------
__global__ __launch_bounds__(256) void build_B(
    const float* __restrict__ A, const float* __restrict__ W,
    float* __restrict__ Bmat)
{
    int e = blockIdx.x;
    for (int c = threadIdx.x; c < BROW; c += 256) {
        float v = 0.f;
        if (e < EE && c < NUSE) {
            int i = c / 28, j = c % 28;
            if (j < 25)       v = A[((size_t)i * EE + e) * DD + j];
            else if (j == 25) v = W[(size_t)e * DD + i];
        }
        Bmat[(size_t)e * BROW + c] = v;
    }
}

// ---------------- embT[k][m] = emb[m][k] (pure copy; zeros for k>=EE, m>=VOCAB) ----------------
__global__ __launch_bounds__(256) void transpose_emb(
    const float* __restrict__ emb, float* __restrict__ embT)
{
    __shared__ float t[64][65];
    int m0 = blockIdx.x * 64, k0 = blockIdx.y * 64;
    int tx = threadIdx.x & 63, ty = threadIdx.x >> 6;   // ty 0..3
#pragma unroll
    for (int it = 0; it < 16; ++it) {
        int m = m0 + ty * 16 + it;
        int k = k0 + tx;
        t[tx][ty * 16 + it] = (m < VOCAB && k < EE) ? emb[(size_t)m * EE + k] : 0.f;
    }
    __syncthreads();
#pragma unroll
    for (int it = 0; it < 16; ++it) {
        int kl = ty * 16 + it;
        int k = k0 + kl;
        if (k < KP) embT[(size_t)k * EMT + m0 + tx] = t[kl][tx];
    }
}

// ---------------- GEMM v6: T3 inner loop (bit-frozen), persistent grid + split tail ----------
// Phase A: 1024 full 128x256 tiles = exactly 2 rounds over 512 blocks.
// Phase B: remaining 149 tiles as 298 128x128 subtiles = ~0.5 round.
// Every output element keeps the identical ascending-k fmaf chain -> T bit-identical to T3.
__global__ __launch_bounds__(256, 1) void gemm_T6(
    const float* __restrict__ embT,  // [KP][EMT] k-major
    const float* __restrict__ Bmat,  // [KP][BROW]
    float* __restrict__ T)           // [VOCAB][TROW]
{
    __shared__ float As[2][16 * 128];   // 16 KB (flat [16][128])
    __shared__ float Bs[2][16 * 256];   // 32 KB (flat [16][256]; phase B uses flat [16][128])
    int tid = threadIdx.x;
    int tx = tid & 15, ty = tid >> 4;
    int wave = tid >> 6, lane = tid & 63;
    int krow = lane >> 5;
    int col4 = (lane & 31) * 4;

    float acc[8][16];

    // ---------------- phase A: full 128x256 tiles ----------------
    for (int t = blockIdx.x; t < FULLT; t += gridDim.x) {
        int mi = t / 3, ni = t - mi * 3;
        int m0 = mi * 128, n0 = ni * 256;

#pragma unroll
        for (int a = 0; a < 8; ++a)
#pragma unroll
            for (int c = 0; c < 16; ++c) acc[a][c] = 0.f;

        auto dma_tile = [&](int k0, int buf) {
#pragma unroll
            for (int j = 0; j < 2; ++j) {          // As: 2 instr/wave, 2 rows each
                int r0 = wave * 4 + j * 2;
                int k = k0 + r0 + krow;
                GLOAD_LDS16(embT + (size_t)k * EMT + m0 + col4, &As[buf][r0 * 128]);
            }
#pragma unroll
            for (int j = 0; j < 4; ++j) {          // Bs: 4 instr/wave, 1 row each
                int r = wave * 4 + j;
                GLOAD_LDS16(Bmat + (size_t)(k0 + r) * BROW + n0 + lane * 4,
                            &Bs[buf][r * 256]);
            }
        };

        dma_tile(0, 0);
        __syncthreads();

        int buf = 0;
        for (int k0 = 0; k0 < KP; k0 += 16) {
            if (k0 + 16 < KP) dma_tile(k0 + 16, buf ^ 1);
#pragma unroll
            for (int kk = 0; kk < 16; ++kk) {      // global k strictly ascending
                const float* Ar = &As[buf][kk * 128];
                const float* Br = &Bs[buf][kk * 256];
                float4 a0 = *(const float4*)&Ar[ty * 4];
                float4 a1 = *(const float4*)&Ar[64 + ty * 4];
                float4 b0 = *(const float4*)&Br[tx * 4];
                float4 b1 = *(const float4*)&Br[64 + tx * 4];
                float4 b2 = *(const float4*)&Br[128 + tx * 4];
                float4 b3 = *(const float4*)&Br[192 + tx * 4];
                float av[8]  = {a0.x, a0.y, a0.z, a0.w, a1.x, a1.y, a1.z, a1.w};
                float bv[16] = {b0.x, b0.y, b0.z, b0.w, b1.x, b1.y, b1.z, b1.w,
                                b2.x, b2.y, b2.z, b2.w, b3.x, b3.y, b3.z, b3.w};
#pragma unroll
                for (int a = 0; a < 8; ++a)
#pragma unroll
                    for (int c = 0; c < 16; ++c)
                        acc[a][c] = fmaf(av[a], bv[c], acc[a][c]);
            }
            __syncthreads();
            buf ^= 1;
        }

#pragma unroll
        for (int gi = 0; gi < 2; ++gi) {
#pragma unroll
            for (int r = 0; r < 4; ++r) {
                int m = m0 + gi * 64 + ty * 4 + r;
                if (m < VOCAB) {
                    float* row = T + (size_t)m * TROW;
#pragma unroll
                    for (int gc = 0; gc < 4; ++gc) {
                        int n = n0 + gc * 64 + tx * 4;
                        if (n < TROW) {
                            int a = gi * 4 + r, c = gc * 4;
                            *(float4*)(row + n) = make_float4(
                                acc[a][c], acc[a][c + 1], acc[a][c + 2], acc[a][c + 3]);
                        }
                    }
                }
            }
        }
    }

    // ---------------- phase B: 128x128 tail subtiles ----------------
    for (int s = blockIdx.x; s < SUBT; s += gridDim.x) {
        int p   = FULLT + (s >> 1);
        int sub = s & 1;
        int mi = p / 3, ni = p - mi * 3;
        int m0 = mi * 128, n0 = ni * 256 + sub * 128;

#pragma unroll
        for (int a = 0; a < 8; ++a)
#pragma unroll
            for (int c = 0; c < 8; ++c) acc[a][c] = 0.f;

        auto dma_sub = [&](int k0, int buf) {
#pragma unroll
            for (int j = 0; j < 2; ++j) {          // As: 2 instr/wave, 2 rows each
                int r0 = wave * 4 + j * 2;
                int k = k0 + r0 + krow;
                GLOAD_LDS16(embT + (size_t)k * EMT + m0 + col4, &As[buf][r0 * 128]);
                // Bs (128-wide, flat rows): same 2-rows-per-instr pattern
                GLOAD_LDS16(Bmat + (size_t)k * BROW + n0 + col4, &Bs[buf][r0 * 128]);
            }
        };

        dma_sub(0, 0);
        __syncthreads();

        int buf = 0;
        for (int k0 = 0; k0 < KP; k0 += 16) {
            if (k0 + 16 < KP) dma_sub(k0 + 16, buf ^ 1);
#pragma unroll
            for (int kk = 0; kk < 16; ++kk) {      // global k strictly ascending
                const float* Ar = &As[buf][kk * 128];
                const float* Br = &Bs[buf][kk * 128];
                float4 a0 = *(const float4*)&Ar[ty * 4];
                float4 a1 = *(const float4*)&Ar[64 + ty * 4];
                float4 b0 = *(const float4*)&Br[tx * 4];
                float4 b1 = *(const float4*)&Br[64 + tx * 4];
                float av[8] = {a0.x, a0.y, a0.z, a0.w, a1.x, a1.y, a1.z, a1.w};
                float bv[8] = {b0.x, b0.y, b0.z, b0.w, b1.x, b1.y, b1.z, b1.w};
#pragma unroll
                for (int a = 0; a < 8; ++a)
#pragma unroll
                    for (int c = 0; c < 8; ++c)
                        acc[a][c] = fmaf(av[a], bv[c], acc[a][c]);
            }
            __syncthreads();
            buf ^= 1;
        }

#pragma unroll
        for (int gi = 0; gi < 2; ++gi) {
#pragma unroll
            for (int r = 0; r < 4; ++r) {
                int m = m0 + gi * 64 + ty * 4 + r;
                if (m < VOCAB) {
                    float* row = T + (size_t)m * TROW;
#pragma unroll
                    for (int gc = 0; gc < 2; ++gc) {
                        int n = n0 + gc * 64 + tx * 4;
                        if (n < TROW) {
                            int a = gi * 4 + r, c = gc * 4;
                            *(float4*)(row + n) = make_float4(
                                acc[a][c], acc[a][c + 1], acc[a][c + 2], acc[a][c + 3]);
                        }
                    }
                }
            }
        }
    }
}

// ---------------- fallback GEMM (R11): register-prefetch pipeline ----------------
__global__ __launch_bounds__(256, 2) void gemm_T(
    const float* __restrict__ emb, const float* __restrict__ Bmat,
    float* __restrict__ T)
{
    __shared__ float As[2][16][132];
    __shared__ float Bs[2][16][132];
    int tid = threadIdx.x;
    int tx = tid & 15, ty = tid >> 4;
    int m0 = blockIdx.x * 128, n0 = blockIdx.y * 128;
    float acc[8][8];
#pragma unroll
    for (int a = 0; a < 8; ++a)
#pragma unroll
        for (int c = 0; c < 8; ++c) acc[a][c] = 0.f;
    float ar[8]; float4 br[2];
    int kl0 = tid >> 5, nl0 = (tid & 31) * 4;
#pragma unroll
    for (int it = 0; it < 8; ++it) {
        int m = m0 + ty + 16 * it, k = tx;
        ar[it] = (m < VOCAB && k < EE) ? emb[(size_t)m * EE + k] : 0.f;
    }
#pragma unroll
    for (int it = 0; it < 2; ++it) {
        int k = kl0 + 8 * it;
        br[it] = (k < EE) ? *(const float4*)(Bmat + (size_t)k * BROW + n0 + nl0)
                          : make_float4(0.f, 0.f, 0.f, 0.f);
    }
#pragma unroll
    for (int it = 0; it < 8; ++it) As[0][tx][ty + 16 * it] = ar[it];
#pragma unroll
    for (int it = 0; it < 2; ++it) *(float4*)(&Bs[0][kl0 + 8 * it][nl0]) = br[it];
    __syncthreads();
    int buf = 0;
    for (int k0 = 0; k0 < EE; k0 += 16) {
        int k1 = k0 + 16;
        bool more = (k1 < EE);
        if (more) {
#pragma unroll
            for (int it = 0; it < 8; ++it) {
                int m = m0 + ty + 16 * it, k = k1 + tx;
                ar[it] = (m < VOCAB && k < EE) ? emb[(size_t)m * EE + k] : 0.f;
            }
#pragma unroll
            for (int it = 0; it < 2; ++it) {
                int k = k1 + kl0 + 8 * it;
                br[it] = (k < EE) ? *(const float4*)(Bmat + (size_t)k * BROW + n0 + nl0)
                                  : make_float4(0.f, 0.f, 0.f, 0.f);
            }
        }
#pragma unroll
        for (int kk = 0; kk < 16; ++kk) {
            float4 a0 = *(const float4*)&As[buf][kk][ty * 4];
            float4 a1 = *(const float4*)&As[buf][kk][64 + ty * 4];
            float4 b0 = *(const float4*)&Bs[buf][kk][tx * 4];
            float4 b1 = *(const float4*)&Bs[buf][kk][64 + tx * 4];
            float av[8] = {a0.x, a0.y, a0.z, a0.w, a1.x, a1.y, a1.z, a1.w};
            float bv[8] = {b0.x, b0.y, b0.z, b0.w, b1.x, b1.y, b1.z, b1.w};
#pragma unroll
            for (int a = 0; a < 8; ++a)
#pragma unroll
                for (int c = 0; c < 8; ++c)
                    acc[a][c] = fmaf(av[a], bv[c], acc[a][c]);
        }
        if (more) {
            int nb = buf ^ 1;
#pragma unroll
            for (int it = 0; it < 8; ++it) As[nb][tx][ty + 16 * it] = ar[it];
#pragma unroll
            for (int it = 0; it < 2; ++it) *(float4*)(&Bs[nb][kl0 + 8 * it][nl0]) = br[it];
            __syncthreads();
            buf = nb;
        }
    }
#pragma unroll
    for (int gi = 0; gi < 2; ++gi) {
#pragma unroll
        for (int r = 0; r < 4; ++r) {
            int m = m0 + gi * 64 + ty * 4 + r;
            if (m < VOCAB) {
                float* row = T + (size_t)m * TROW;
#pragma unroll
                for (int gc = 0; gc < 2; ++gc) {
                    int n = n0 + gc * 64 + tx * 4;
                    if (n < TROW) {
                        int a = gi * 4 + r, c = gc * 4;
                        *(float4*)(row + n) = make_float4(
                            acc[a][c], acc[a][c + 1], acc[a][c + 2], acc[a][c + 3]);
                    }
                }
            }
        }
    }
}

// ---------------- scan: frozen numerics, depth-3 prefetch (4 rotating buffers) ----------------
__global__ __launch_bounds__(256, 1) void rnn_scan_np6(
    const int*   __restrict__ words,
    const float* __restrict__ T,
    const float* __restrict__ V,
    const float* __restrict__ bvec,
    const float* __restrict__ outW,
    const float* __restrict__ outB,
    float* __restrict__ out,
    int B)
{
    int tid = threadIdx.x;
    int g = tid >> 5, i = tid & 31;
    int b = blockIdx.x * 8 + g;
    bool act = (i < DD) && (b < B);
    int ii = (i < DD) ? i : (DD - 1);
    int bsafe = (b < B) ? b : 0;
    const int* wr = words + (size_t)bsafe * SEQ;

    float Vcol[DD];
#pragma unroll
    for (int j = 0; j < DD; ++j) Vcol[j] = V[j * DD + ii];
    float bi = bvec[ii];

    float hr[DD];
#pragma unroll
    for (int j = 0; j < DD; ++j) hr[j] = 0.f;
    hr[DD - 1] = 1.f;                // h0 = e_24

    bool sse = ((b & 3) == 0) && ((i & 3) == 0);
    const float* base = T + (size_t)ii * 28;

    float4 A0[7], A1[7], A2[7], A3[7];
    auto LD = [&](float4* dst, int t) {
        const float* R = base + (size_t)wr[t] * TROW;
#pragma unroll
        for (int u = 0; u < 7; ++u) dst[u] = *(const float4*)(R + u * 4);
    };

    float hnew = 0.f;
    auto STEP = [&](const float4* C) {
        float Tj[28];
#pragma unroll
        for (int u = 0; u < 7; ++u) {
            Tj[u * 4 + 0] = C[u].x; Tj[u * 4 + 1] = C[u].y;
            Tj[u * 4 + 2] = C[u].z; Tj[u * 4 + 3] = C[u].w;
        }
        float qv = Tj[25];
        float a;
        if (sse) {
            float p0 = 0.f, p1 = 0.f, p2 = 0.f, p3 = 0.f;
#pragma unroll
            for (int j = 0; j < 24; j += 4) {
                p0 = __fadd_rn(p0, __fmul_rn(Tj[j],     hr[j]));
                p1 = __fadd_rn(p1, __fmul_rn(Tj[j + 1], hr[j + 1]));
                p2 = __fadd_rn(p2, __fmul_rn(Tj[j + 2], hr[j + 2]));
                p3 = __fadd_rn(p3, __fmul_rn(Tj[j + 3], hr[j + 3]));
            }
            float s02 = __fadd_rn(p0, p2);
            float s13 = __fadd_rn(p1, p3);
            a = __fadd_rn(s02, s13);
            a = __fadd_rn(a, __fmul_rn(Tj[24], hr[24]));
        } else {
            a = 0.f;
#pragma unroll
            for (int j = 0; j < DD; ++j)
                a = __fadd_rn(a, __fmul_rn(Tj[j], hr[j]));
        }
        float r2 = 0.f;
#pragma unroll
        for (int j = 0; j < DD; ++j)
            r2 = fmaf(hr[j], Vcol[j], r2);
        float lin = __fadd_rn(__fadd_rn(qv, r2), bi);
        float pre = __fadd_rn(a, lin);
        hnew = act ? (float)tanh((double)pre) : 0.f;
#pragma unroll
        for (int j = 0; j < DD; ++j)
            hr[j] = __shfl(hnew, j, 32);
    };

    LD(A0, 0); LD(A1, 1); LD(A2, 2);
    int t = 0;
    for (; t + 6 < SEQ; t += 4) {            // t = 0,4,...,120
        LD(A3, t + 3); STEP(A0);
        LD(A0, t + 4); STEP(A1);
        LD(A1, t + 5); STEP(A2);
        LD(A2, t + 6); STEP(A3);
    }
    // t == 124: A0<-124, A1<-125, A2<-126 loaded; steps 124..127 remain
    LD(A3, 127);
    STEP(A0); STEP(A1); STEP(A2); STEP(A3);

    if (i < NC && b < B) {
        float acc = 0.f;
#pragma unroll
        for (int j = 0; j < DD; ++j)
            acc = fmaf(hr[j], outW[i * DD + j], acc);
        float l = __fadd_rn(acc, outB[i]);
        out[(size_t)b * NC + i] = (float)(1.0 / (1.0 + exp(-(double)l)));
    }
}

extern "C" void kernel_launch(void* const* d_in, const int* in_sizes, int n_in,
                              void* d_out, int out_size, void* d_ws, size_t ws_size,
                              hipStream_t stream)
{
    const int*   words = (const int*)d_in[0];
    const float* emb   = (const float*)d_in[2];
    const float* A     = (const float*)d_in[3];
    const float* W     = (const float*)d_in[4];
    const float* V     = (const float*)d_in[5];
    const float* bias  = (const float*)d_in[6];
    const float* outW  = (const float*)d_in[7];
    const float* outB  = (const float*)d_in[8];
    float* out = (float*)d_out;
    int B = in_sizes[0] / SEQ;

    const size_t T_OFF    = (size_t)1 << 20;                 // Bmat: 304*768*4 = 0.93 MB
    const size_t EMBT_OFF = (size_t)144 << 20;               // T: 50000*704*4 = 140.8 MB
    const size_t NEED     = EMBT_OFF + (size_t)KP * EMT * 4; // + embT 61 MB ≈ 205 MB
    float* Bmat = (float*)d_ws;
    float* T    = (float*)((char*)d_ws + T_OFF);
    float* embT = (float*)((char*)d_ws + EMBT_OFF);

    build_B<<<KP, 256, 0, stream>>>(A, W, Bmat);
    if (ws_size >= NEED) {
        transpose_emb<<<dim3(EMT / 64, (KP + 63) / 64), 256, 0, stream>>>(emb, embT);
        gemm_T6<<<GEMM_GRID, 256, 0, stream>>>(embT, Bmat, T);
    } else {
        gemm_T<<<dim3((VOCAB + 127) / 128, 6), 256, 0, stream>>>(emb, Bmat, T);
    }
    rnn_scan_np6<<<(B + 7) / 8, 256, 0, stream>>>(words, T, V, bias, outW, outB, out, B);
}

// Round 4
// 514.298 us; speedup vs baseline: 2.7823x; 1.2181x over previous
//
#include <hip/hip_runtime.h>
#include <math.h>

#define VOCAB 50000
#define EE 301
#define KP 304     // padded K (multiple of 16; rows EE..KP-1 are zeros)
#define DD 25
#define SEQ 128
#define NC 5
#define BROW 768   // Bmat cols (scan-order, zero-padded): col i*28+j = A[i][e][j] (j<25), i*28+25 = W[e][i]
#define NUSE 700
#define TROW 704   // T row stride (floats); scan reads i*28 .. i*28+27
#define EMT 50112  // embT row stride (zero-padded cols VOCAB..EMT-1)
#define MTILES 391 // ceil(50000/128)
#define NTILES (MTILES*3)   // 1173 full 128x256 tiles
#define FULLT 1024          // tiles done by gemm_T3a: exactly 2 rounds of 512 slots
#define SUBT ((NTILES - FULLT) * 2)  // 298 half-width (128x128) tail subtiles

// async global->LDS DMA, 16B per lane, lane i lands at ldsbase + i*16
#define GLOAD_LDS16(g, l) __builtin_amdgcn_global_load_lds( \
    (const __attribute__((address_space(1))) void*)(g),     \
    (__attribute__((address_space(3))) void*)(l), 16, 0, 0)

// ---------------- Bmat[e][c'] in scan order; rows EE..KP-1 zero ----------------
__global__ __launch_bounds__(256) void build_B(
    const float* __restrict__ A, const float* __restrict__ W,
    float* __restrict__ Bmat)
{
    int e = blockIdx.x;
    for (int c = threadIdx.x; c < BROW; c += 256) {
        float v = 0.f;
        if (e < EE && c < NUSE) {
            int i = c / 28, j = c % 28;
            if (j < 25)       v = A[((size_t)i * EE + e) * DD + j];
            else if (j == 25) v = W[(size_t)e * DD + i];
        }
        Bmat[(size_t)e * BROW + c] = v;
    }
}

// ---------------- embT[k][m] = emb[m][k] (pure copy; zeros for k>=EE, m>=VOCAB) ----------------
__global__ __launch_bounds__(256) void transpose_emb(
    const float* __restrict__ emb, float* __restrict__ embT)
{
    __shared__ float t[64][65];
    int m0 = blockIdx.x * 64, k0 = blockIdx.y * 64;
    int tx = threadIdx.x & 63, ty = threadIdx.x >> 6;   // ty 0..3
#pragma unroll
    for (int it = 0; it < 16; ++it) {
        int m = m0 + ty * 16 + it;
        int k = k0 + tx;
        t[tx][ty * 16 + it] = (m < VOCAB && k < EE) ? emb[(size_t)m * EE + k] : 0.f;
    }
    __syncthreads();
#pragma unroll
    for (int it = 0; it < 16; ++it) {
        int kl = ty * 16 + it;
        int k = k0 + kl;
        if (k < KP) embT[(size_t)k * EMT + m0 + tx] = t[kl][tx];
    }
}

// ---------------- GEMM phase A: verbatim gemm_T3 body, 1D tile decode ----------------
// Covers tiles t = 0..1023 (mi = t/3, ni = t%3). 1024 blocks = exactly 2 rounds
// at 2 blocks/CU. Inner loop and LDS layout bit-frozen from the proven T3.
__global__ __launch_bounds__(256, 1) void gemm_T3a(
    const float* __restrict__ embT,  // [KP][EMT] k-major
    const float* __restrict__ Bmat,  // [KP][BROW]
    float* __restrict__ T)           // [VOCAB][TROW]
{
    __shared__ float As[2][16][128];   // 16 KB
    __shared__ float Bs[2][16][256];   // 32 KB
    int tid = threadIdx.x;
    int tx = tid & 15, ty = tid >> 4;
    int t = blockIdx.x;
    int mi = t / 3, ni = t - mi * 3;
    int m0 = mi * 128, n0 = ni * 256;
    int wave = tid >> 6, lane = tid & 63;
    int krow = lane >> 5;
    int col4 = (lane & 31) * 4;

    float acc[8][16];
#pragma unroll
    for (int a = 0; a < 8; ++a)
#pragma unroll
        for (int c = 0; c < 16; ++c) acc[a][c] = 0.f;

    auto dma_tile = [&](int k0, int buf) {
#pragma unroll
        for (int j = 0; j < 2; ++j) {          // As: 2 instr/wave, 2 rows each
            int r0 = wave * 4 + j * 2;
            int k = k0 + r0 + krow;
            GLOAD_LDS16(embT + (size_t)k * EMT + m0 + col4, &As[buf][r0][0]);
        }
#pragma unroll
        for (int j = 0; j < 4; ++j) {          // Bs: 4 instr/wave, 1 row each
            int r = wave * 4 + j;
            int k = k0 + r;
            GLOAD_LDS16(Bmat + (size_t)k * BROW + n0 + lane * 4, &Bs[buf][r][0]);
        }
    };

    dma_tile(0, 0);
    __syncthreads();

    int buf = 0;
    for (int k0 = 0; k0 < KP; k0 += 16) {
        if (k0 + 16 < KP) dma_tile(k0 + 16, buf ^ 1);
#pragma unroll
        for (int kk = 0; kk < 16; ++kk) {      // global k strictly ascending
            float4 a0 = *(const float4*)&As[buf][kk][ty * 4];
            float4 a1 = *(const float4*)&As[buf][kk][64 + ty * 4];
            float4 b0 = *(const float4*)&Bs[buf][kk][tx * 4];
            float4 b1 = *(const float4*)&Bs[buf][kk][64 + tx * 4];
            float4 b2 = *(const float4*)&Bs[buf][kk][128 + tx * 4];
            float4 b3 = *(const float4*)&Bs[buf][kk][192 + tx * 4];
            float av[8]  = {a0.x, a0.y, a0.z, a0.w, a1.x, a1.y, a1.z, a1.w};
            float bv[16] = {b0.x, b0.y, b0.z, b0.w, b1.x, b1.y, b1.z, b1.w,
                            b2.x, b2.y, b2.z, b2.w, b3.x, b3.y, b3.z, b3.w};
#pragma unroll
            for (int a = 0; a < 8; ++a)
#pragma unroll
                for (int c = 0; c < 16; ++c)
                    acc[a][c] = fmaf(av[a], bv[c], acc[a][c]);
        }
        __syncthreads();
        buf ^= 1;
    }

    // epilogue: coalesced float4 stores (layout already scan-order)
#pragma unroll
    for (int gi = 0; gi < 2; ++gi) {
#pragma unroll
        for (int r = 0; r < 4; ++r) {
            int m = m0 + gi * 64 + ty * 4 + r;
            if (m < VOCAB) {
                float* row = T + (size_t)m * TROW;
#pragma unroll
                for (int gc = 0; gc < 4; ++gc) {
                    int n = n0 + gc * 64 + tx * 4;
                    if (n < TROW) {
                        int a = gi * 4 + r, c = gc * 4;
                        *(float4*)(row + n) = make_float4(
                            acc[a][c], acc[a][c + 1], acc[a][c + 2], acc[a][c + 3]);
                    }
                }
            }
        }
    }
}

// ---------------- GEMM phase B: tail tiles 1024..1172 as 298 128x128 subtiles ----------------
// Separate kernel (separate regalloc). Same ascending-k fmaf chain per element
// -> T bit-identical to what T3 would produce for these tiles.
__global__ __launch_bounds__(256, 1) void gemm_T3t(
    const float* __restrict__ embT,  // [KP][EMT] k-major
    const float* __restrict__ Bmat,  // [KP][BROW]
    float* __restrict__ T)           // [VOCAB][TROW]
{
    __shared__ float As[2][16][128];   // 16 KB
    __shared__ float Bs[2][16][128];   // 16 KB
    int tid = threadIdx.x;
    int tx = tid & 15, ty = tid >> 4;
    int s = blockIdx.x;                  // 0..297
    int p = FULLT + (s >> 1), sub = s & 1;
    int mi = p / 3, ni = p - mi * 3;
    int m0 = mi * 128, n0 = ni * 256 + sub * 128;
    int wave = tid >> 6, lane = tid & 63;
    int krow = lane >> 5;
    int col4 = (lane & 31) * 4;

    float acc[8][8];
#pragma unroll
    for (int a = 0; a < 8; ++a)
#pragma unroll
        for (int c = 0; c < 8; ++c) acc[a][c] = 0.f;

    auto dma_tile = [&](int k0, int buf) {
#pragma unroll
        for (int j = 0; j < 2; ++j) {          // 2 instr/wave each for As and Bs, 2 rows/instr
            int r0 = wave * 4 + j * 2;
            int k = k0 + r0 + krow;
            GLOAD_LDS16(embT + (size_t)k * EMT + m0 + col4, &As[buf][r0][0]);
            GLOAD_LDS16(Bmat + (size_t)k * BROW + n0 + col4, &Bs[buf][r0][0]);
        }
    };

    dma_tile(0, 0);
    __syncthreads();

    int buf = 0;
    for (int k0 = 0; k0 < KP; k0 += 16) {
        if (k0 + 16 < KP) dma_tile(k0 + 16, buf ^ 1);
#pragma unroll
        for (int kk = 0; kk < 16; ++kk) {      // global k strictly ascending
            float4 a0 = *(const float4*)&As[buf][kk][ty * 4];
            float4 a1 = *(const float4*)&As[buf][kk][64 + ty * 4];
            float4 b0 = *(const float4*)&Bs[buf][kk][tx * 4];
            float4 b1 = *(const float4*)&Bs[buf][kk][64 + tx * 4];
            float av[8] = {a0.x, a0.y, a0.z, a0.w, a1.x, a1.y, a1.z, a1.w};
            float bv[8] = {b0.x, b0.y, b0.z, b0.w, b1.x, b1.y, b1.z, b1.w};
#pragma unroll
            for (int a = 0; a < 8; ++a)
#pragma unroll
                for (int c = 0; c < 8; ++c)
                    acc[a][c] = fmaf(av[a], bv[c], acc[a][c]);
        }
        __syncthreads();
        buf ^= 1;
    }

#pragma unroll
    for (int gi = 0; gi < 2; ++gi) {
#pragma unroll
        for (int r = 0; r < 4; ++r) {
            int m = m0 + gi * 64 + ty * 4 + r;
            if (m < VOCAB) {
                float* row = T + (size_t)m * TROW;
#pragma unroll
                for (int gc = 0; gc < 2; ++gc) {
                    int n = n0 + gc * 64 + tx * 4;
                    if (n < TROW) {
                        int a = gi * 4 + r, c = gc * 4;
                        *(float4*)(row + n) = make_float4(
                            acc[a][c], acc[a][c + 1], acc[a][c + 2], acc[a][c + 3]);
                    }
                }
            }
        }
    }
}

// ---------------- fallback GEMM (R11): register-prefetch pipeline ----------------
__global__ __launch_bounds__(256, 2) void gemm_T(
    const float* __restrict__ emb, const float* __restrict__ Bmat,
    float* __restrict__ T)
{
    __shared__ float As[2][16][132];
    __shared__ float Bs[2][16][132];
    int tid = threadIdx.x;
    int tx = tid & 15, ty = tid >> 4;
    int m0 = blockIdx.x * 128, n0 = blockIdx.y * 128;
    float acc[8][8];
#pragma unroll
    for (int a = 0; a < 8; ++a)
#pragma unroll
        for (int c = 0; c < 8; ++c) acc[a][c] = 0.f;
    float ar[8]; float4 br[2];
    int kl0 = tid >> 5, nl0 = (tid & 31) * 4;
#pragma unroll
    for (int it = 0; it < 8; ++it) {
        int m = m0 + ty + 16 * it, k = tx;
        ar[it] = (m < VOCAB && k < EE) ? emb[(size_t)m * EE + k] : 0.f;
    }
#pragma unroll
    for (int it = 0; it < 2; ++it) {
        int k = kl0 + 8 * it;
        br[it] = (k < EE) ? *(const float4*)(Bmat + (size_t)k * BROW + n0 + nl0)
                          : make_float4(0.f, 0.f, 0.f, 0.f);
    }
#pragma unroll
    for (int it = 0; it < 8; ++it) As[0][tx][ty + 16 * it] = ar[it];
#pragma unroll
    for (int it = 0; it < 2; ++it) *(float4*)(&Bs[0][kl0 + 8 * it][nl0]) = br[it];
    __syncthreads();
    int buf = 0;
    for (int k0 = 0; k0 < EE; k0 += 16) {
        int k1 = k0 + 16;
        bool more = (k1 < EE);
        if (more) {
#pragma unroll
            for (int it = 0; it < 8; ++it) {
                int m = m0 + ty + 16 * it, k = k1 + tx;
                ar[it] = (m < VOCAB && k < EE) ? emb[(size_t)m * EE + k] : 0.f;
            }
#pragma unroll
            for (int it = 0; it < 2; ++it) {
                int k = k1 + kl0 + 8 * it;
                br[it] = (k < EE) ? *(const float4*)(Bmat + (size_t)k * BROW + n0 + nl0)
                                  : make_float4(0.f, 0.f, 0.f, 0.f);
            }
        }
#pragma unroll
        for (int kk = 0; kk < 16; ++kk) {
            float4 a0 = *(const float4*)&As[buf][kk][ty * 4];
            float4 a1 = *(const float4*)&As[buf][kk][64 + ty * 4];
            float4 b0 = *(const float4*)&Bs[buf][kk][tx * 4];
            float4 b1 = *(const float4*)&Bs[buf][kk][64 + tx * 4];
            float av[8] = {a0.x, a0.y, a0.z, a0.w, a1.x, a1.y, a1.z, a1.w};
            float bv[8] = {b0.x, b0.y, b0.z, b0.w, b1.x, b1.y, b1.z, b1.w};
#pragma unroll
            for (int a = 0; a < 8; ++a)
#pragma unroll
                for (int c = 0; c < 8; ++c)
                    acc[a][c] = fmaf(av[a], bv[c], acc[a][c]);
        }
        if (more) {
            int nb = buf ^ 1;
#pragma unroll
            for (int it = 0; it < 8; ++it) As[nb][tx][ty + 16 * it] = ar[it];
#pragma unroll
            for (int it = 0; it < 2; ++it) *(float4*)(&Bs[nb][kl0 + 8 * it][nl0]) = br[it];
            __syncthreads();
            buf = nb;
        }
    }
#pragma unroll
    for (int gi = 0; gi < 2; ++gi) {
#pragma unroll
        for (int r = 0; r < 4; ++r) {
            int m = m0 + gi * 64 + ty * 4 + r;
            if (m < VOCAB) {
                float* row = T + (size_t)m * TROW;
#pragma unroll
                for (int gc = 0; gc < 2; ++gc) {
                    int n = n0 + gc * 64 + tx * 4;
                    if (n < TROW) {
                        int a = gi * 4 + r, c = gc * 4;
                        *(float4*)(row + n) = make_float4(
                            acc[a][c], acc[a][c + 1], acc[a][c + 2], acc[a][c + 3]);
                    }
                }
            }
        }
    }
}

// ---------------- scan: frozen numerics, depth-3 prefetch (4 rotating buffers) ----------------
__global__ __launch_bounds__(256, 1) void rnn_scan_np6(
    const int*   __restrict__ words,
    const float* __restrict__ T,
    const float* __restrict__ V,
    const float* __restrict__ bvec,
    const float* __restrict__ outW,
    const float* __restrict__ outB,
    float* __restrict__ out,
    int B)
{
    int tid = threadIdx.x;
    int g = tid >> 5, i = tid & 31;
    int b = blockIdx.x * 8 + g;
    bool act = (i < DD) && (b < B);
    int ii = (i < DD) ? i : (DD - 1);
    int bsafe = (b < B) ? b : 0;
    const int* wr = words + (size_t)bsafe * SEQ;

    float Vcol[DD];
#pragma unroll
    for (int j = 0; j < DD; ++j) Vcol[j] = V[j * DD + ii];
    float bi = bvec[ii];

    float hr[DD];
#pragma unroll
    for (int j = 0; j < DD; ++j) hr[j] = 0.f;
    hr[DD - 1] = 1.f;                // h0 = e_24

    bool sse = ((b & 3) == 0) && ((i & 3) == 0);
    const float* base = T + (size_t)ii * 28;

    float4 A0[7], A1[7], A2[7], A3[7];
    auto LD = [&](float4* dst, int t) {
        const float* R = base + (size_t)wr[t] * TROW;
#pragma unroll
        for (int u = 0; u < 7; ++u) dst[u] = *(const float4*)(R + u * 4);
    };

    float hnew = 0.f;
    auto STEP = [&](const float4* C) {
        float Tj[28];
#pragma unroll
        for (int u = 0; u < 7; ++u) {
            Tj[u * 4 + 0] = C[u].x; Tj[u * 4 + 1] = C[u].y;
            Tj[u * 4 + 2] = C[u].z; Tj[u * 4 + 3] = C[u].w;
        }
        float qv = Tj[25];
        float a;
        if (sse) {
            float p0 = 0.f, p1 = 0.f, p2 = 0.f, p3 = 0.f;
#pragma unroll
            for (int j = 0; j < 24; j += 4) {
                p0 = __fadd_rn(p0, __fmul_rn(Tj[j],     hr[j]));
                p1 = __fadd_rn(p1, __fmul_rn(Tj[j + 1], hr[j + 1]));
                p2 = __fadd_rn(p2, __fmul_rn(Tj[j + 2], hr[j + 2]));
                p3 = __fadd_rn(p3, __fmul_rn(Tj[j + 3], hr[j + 3]));
            }
            float s02 = __fadd_rn(p0, p2);
            float s13 = __fadd_rn(p1, p3);
            a = __fadd_rn(s02, s13);
            a = __fadd_rn(a, __fmul_rn(Tj[24], hr[24]));
        } else {
            a = 0.f;
#pragma unroll
            for (int j = 0; j < DD; ++j)
                a = __fadd_rn(a, __fmul_rn(Tj[j], hr[j]));
        }
        float r2 = 0.f;
#pragma unroll
        for (int j = 0; j < DD; ++j)
            r2 = fmaf(hr[j], Vcol[j], r2);
        float lin = __fadd_rn(__fadd_rn(qv, r2), bi);
        float pre = __fadd_rn(a, lin);
        hnew = act ? (float)tanh((double)pre) : 0.f;
#pragma unroll
        for (int j = 0; j < DD; ++j)
            hr[j] = __shfl(hnew, j, 32);
    };

    LD(A0, 0); LD(A1, 1); LD(A2, 2);
    int t = 0;
    for (; t + 6 < SEQ; t += 4) {            // t = 0,4,...,120
        LD(A3, t + 3); STEP(A0);
        LD(A0, t + 4); STEP(A1);
        LD(A1, t + 5); STEP(A2);
        LD(A2, t + 6); STEP(A3);
    }
    // t == 124: A0<-124, A1<-125, A2<-126 loaded; steps 124..127 remain
    LD(A3, 127);
    STEP(A0); STEP(A1); STEP(A2); STEP(A3);

    if (i < NC && b < B) {
        float acc = 0.f;
#pragma unroll
        for (int j = 0; j < DD; ++j)
            acc = fmaf(hr[j], outW[i * DD + j], acc);
        float l = __fadd_rn(acc, outB[i]);
        out[(size_t)b * NC + i] = (float)(1.0 / (1.0 + exp(-(double)l)));
    }
}

extern "C" void kernel_launch(void* const* d_in, const int* in_sizes, int n_in,
                              void* d_out, int out_size, void* d_ws, size_t ws_size,
                              hipStream_t stream)
{
    const int*   words = (const int*)d_in[0];
    const float* emb   = (const float*)d_in[2];
    const float* A     = (const float*)d_in[3];
    const float* W     = (const float*)d_in[4];
    const float* V     = (const float*)d_in[5];
    const float* bias  = (const float*)d_in[6];
    const float* outW  = (const float*)d_in[7];
    const float* outB  = (const float*)d_in[8];
    float* out = (float*)d_out;
    int B = in_sizes[0] / SEQ;

    const size_t T_OFF    = (size_t)1 << 20;                 // Bmat: 304*768*4 = 0.93 MB
    const size_t EMBT_OFF = (size_t)144 << 20;               // T: 50000*704*4 = 140.8 MB
    const size_t NEED     = EMBT_OFF + (size_t)KP * EMT * 4; // + embT 61 MB ≈ 205 MB
    float* Bmat = (float*)d_ws;
    float* T    = (float*)((char*)d_ws + T_OFF);
    float* embT = (float*)((char*)d_ws + EMBT_OFF);

    build_B<<<KP, 256, 0, stream>>>(A, W, Bmat);
    if (ws_size >= NEED) {
        transpose_emb<<<dim3(EMT / 64, (KP + 63) / 64), 256, 0, stream>>>(emb, embT);
        gemm_T3a<<<FULLT, 256, 0, stream>>>(embT, Bmat, T);
        gemm_T3t<<<SUBT, 256, 0, stream>>>(embT, Bmat, T);
    } else {
        gemm_T<<<dim3((VOCAB + 127) / 128, 6), 256, 0, stream>>>(emb, Bmat, T);
    }
    rnn_scan_np6<<<(B + 7) / 8, 256, 0, stream>>>(words, T, V, bias, outW, outB, out, B);
}

// Round 5
// 494.437 us; speedup vs baseline: 2.8941x; 1.0402x over previous
//
#include <hip/hip_runtime.h>
#include <math.h>

#define VOCAB 50000
#define EE 301
#define KP 304     // padded K (multiple of 16; rows EE..KP-1 are zeros)
#define DD 25
#define SEQ 128
#define NC 5
#define BROW 768   // Bmat cols (scan-order, zero-padded): col i*28+j = A[i][e][j] (j<25), i*28+25 = W[e][i]
#define NUSE 700
#define TROW 704   // T row stride (floats); scan reads i*28 .. i*28+27
#define EMT 50112  // embT row stride (zero-padded cols VOCAB..EMT-1)

// async global->LDS DMA, 16B per lane, lane i lands at ldsbase + i*16
#define GLOAD_LDS16(g, l) __builtin_amdgcn_global_load_lds( \
    (const __attribute__((address_space(1))) void*)(g),     \
    (__attribute__((address_space(3))) void*)(l), 16, 0, 0)

// ---------------- Bmat[e][c'] in scan order; rows EE..KP-1 zero ----------------
__global__ __launch_bounds__(256) void build_B(
    const float* __restrict__ A, const float* __restrict__ W,
    float* __restrict__ Bmat)
{
    int e = blockIdx.x;
    for (int c = threadIdx.x; c < BROW; c += 256) {
        float v = 0.f;
        if (e < EE && c < NUSE) {
            int i = c / 28, j = c % 28;
            if (j < 25)       v = A[((size_t)i * EE + e) * DD + j];
            else if (j == 25) v = W[(size_t)e * DD + i];
        }
        Bmat[(size_t)e * BROW + c] = v;
    }
}

// ---------------- embT[k][m] = emb[m][k] (pure copy; zeros for k>=EE, m>=VOCAB) ----------------
__global__ __launch_bounds__(256) void transpose_emb(
    const float* __restrict__ emb, float* __restrict__ embT)
{
    __shared__ float t[64][65];
    int m0 = blockIdx.x * 64, k0 = blockIdx.y * 64;
    int tx = threadIdx.x & 63, ty = threadIdx.x >> 6;   // ty 0..3
#pragma unroll
    for (int it = 0; it < 16; ++it) {
        int m = m0 + ty * 16 + it;
        int k = k0 + tx;
        t[tx][ty * 16 + it] = (m < VOCAB && k < EE) ? emb[(size_t)m * EE + k] : 0.f;
    }
    __syncthreads();
#pragma unroll
    for (int it = 0; it < 16; ++it) {
        int kl = ty * 16 + it;
        int k = k0 + kl;
        if (k < KP) embT[(size_t)k * EMT + m0 + tx] = t[kl][tx];
    }
}

// ---------------- GEMM v3 (verbatim round-1 proven 277 us): 128m x 256n, 8x16 microtile ----
// ascending-k fmaf chain per element (k 0..303, zero tail) -- bit-frozen.
__global__ __launch_bounds__(256, 1) void gemm_T3(
    const float* __restrict__ embT,  // [KP][EMT] k-major
    const float* __restrict__ Bmat,  // [KP][BROW]
    float* __restrict__ T)           // [VOCAB][TROW]
{
    __shared__ float As[2][16][128];   // 16 KB
    __shared__ float Bs[2][16][256];   // 32 KB
    int tid = threadIdx.x;
    int tx = tid & 15, ty = tid >> 4;
    int m0 = blockIdx.x * 128, n0 = blockIdx.y * 256;
    int wave = tid >> 6, lane = tid & 63;
    int krow = lane >> 5;
    int col4 = (lane & 31) * 4;

    float acc[8][16];
#pragma unroll
    for (int a = 0; a < 8; ++a)
#pragma unroll
        for (int c = 0; c < 16; ++c) acc[a][c] = 0.f;

    auto dma_tile = [&](int k0, int buf) {
#pragma unroll
        for (int j = 0; j < 2; ++j) {          // As: 2 instr/wave, 2 rows each
            int r0 = wave * 4 + j * 2;
            int k = k0 + r0 + krow;
            GLOAD_LDS16(embT + (size_t)k * EMT + m0 + col4, &As[buf][r0][0]);
        }
#pragma unroll
        for (int j = 0; j < 4; ++j) {          // Bs: 4 instr/wave, 1 row each
            int r = wave * 4 + j;
            int k = k0 + r;
            GLOAD_LDS16(Bmat + (size_t)k * BROW + n0 + lane * 4, &Bs[buf][r][0]);
        }
    };

    dma_tile(0, 0);
    __syncthreads();

    int buf = 0;
    for (int k0 = 0; k0 < KP; k0 += 16) {
        if (k0 + 16 < KP) dma_tile(k0 + 16, buf ^ 1);
#pragma unroll
        for (int kk = 0; kk < 16; ++kk) {      // global k strictly ascending
            float4 a0 = *(const float4*)&As[buf][kk][ty * 4];
            float4 a1 = *(const float4*)&As[buf][kk][64 + ty * 4];
            float4 b0 = *(const float4*)&Bs[buf][kk][tx * 4];
            float4 b1 = *(const float4*)&Bs[buf][kk][64 + tx * 4];
            float4 b2 = *(const float4*)&Bs[buf][kk][128 + tx * 4];
            float4 b3 = *(const float4*)&Bs[buf][kk][192 + tx * 4];
            float av[8]  = {a0.x, a0.y, a0.z, a0.w, a1.x, a1.y, a1.z, a1.w};
            float bv[16] = {b0.x, b0.y, b0.z, b0.w, b1.x, b1.y, b1.z, b1.w,
                            b2.x, b2.y, b2.z, b2.w, b3.x, b3.y, b3.z, b3.w};
#pragma unroll
            for (int a = 0; a < 8; ++a)
#pragma unroll
                for (int c = 0; c < 16; ++c)
                    acc[a][c] = fmaf(av[a], bv[c], acc[a][c]);
        }
        __syncthreads();
        buf ^= 1;
    }

    // epilogue: coalesced float4 stores (layout already scan-order)
#pragma unroll
    for (int gi = 0; gi < 2; ++gi) {
#pragma unroll
        for (int r = 0; r < 4; ++r) {
            int m = m0 + gi * 64 + ty * 4 + r;
            if (m < VOCAB) {
                float* row = T + (size_t)m * TROW;
#pragma unroll
                for (int gc = 0; gc < 4; ++gc) {
                    int n = n0 + gc * 64 + tx * 4;
                    if (n < TROW) {
                        int a = gi * 4 + r, c = gc * 4;
                        *(float4*)(row + n) = make_float4(
                            acc[a][c], acc[a][c + 1], acc[a][c + 2], acc[a][c + 3]);
                    }
                }
            }
        }
    }
}

// ---------------- fallback GEMM (R11): register-prefetch pipeline ----------------
__global__ __launch_bounds__(256, 2) void gemm_T(
    const float* __restrict__ emb, const float* __restrict__ Bmat,
    float* __restrict__ T)
{
    __shared__ float As[2][16][132];
    __shared__ float Bs[2][16][132];
    int tid = threadIdx.x;
    int tx = tid & 15, ty = tid >> 4;
    int m0 = blockIdx.x * 128, n0 = blockIdx.y * 128;
    float acc[8][8];
#pragma unroll
    for (int a = 0; a < 8; ++a)
#pragma unroll
        for (int c = 0; c < 8; ++c) acc[a][c] = 0.f;
    float ar[8]; float4 br[2];
    int kl0 = tid >> 5, nl0 = (tid & 31) * 4;
#pragma unroll
    for (int it = 0; it < 8; ++it) {
        int m = m0 + ty + 16 * it, k = tx;
        ar[it] = (m < VOCAB && k < EE) ? emb[(size_t)m * EE + k] : 0.f;
    }
#pragma unroll
    for (int it = 0; it < 2; ++it) {
        int k = kl0 + 8 * it;
        br[it] = (k < EE) ? *(const float4*)(Bmat + (size_t)k * BROW + n0 + nl0)
                          : make_float4(0.f, 0.f, 0.f, 0.f);
    }
#pragma unroll
    for (int it = 0; it < 8; ++it) As[0][tx][ty + 16 * it] = ar[it];
#pragma unroll
    for (int it = 0; it < 2; ++it) *(float4*)(&Bs[0][kl0 + 8 * it][nl0]) = br[it];
    __syncthreads();
    int buf = 0;
    for (int k0 = 0; k0 < EE; k0 += 16) {
        int k1 = k0 + 16;
        bool more = (k1 < EE);
        if (more) {
#pragma unroll
            for (int it = 0; it < 8; ++it) {
                int m = m0 + ty + 16 * it, k = k1 + tx;
                ar[it] = (m < VOCAB && k < EE) ? emb[(size_t)m * EE + k] : 0.f;
            }
#pragma unroll
            for (int it = 0; it < 2; ++it) {
                int k = k1 + kl0 + 8 * it;
                br[it] = (k < EE) ? *(const float4*)(Bmat + (size_t)k * BROW + n0 + nl0)
                                  : make_float4(0.f, 0.f, 0.f, 0.f);
            }
        }
#pragma unroll
        for (int kk = 0; kk < 16; ++kk) {
            float4 a0 = *(const float4*)&As[buf][kk][ty * 4];
            float4 a1 = *(const float4*)&As[buf][kk][64 + ty * 4];
            float4 b0 = *(const float4*)&Bs[buf][kk][tx * 4];
            float4 b1 = *(const float4*)&Bs[buf][kk][64 + tx * 4];
            float av[8] = {a0.x, a0.y, a0.z, a0.w, a1.x, a1.y, a1.z, a1.w};
            float bv[8] = {b0.x, b0.y, b0.z, b0.w, b1.x, b1.y, b1.z, b1.w};
#pragma unroll
            for (int a = 0; a < 8; ++a)
#pragma unroll
                for (int c = 0; c < 8; ++c)
                    acc[a][c] = fmaf(av[a], bv[c], acc[a][c]);
        }
        if (more) {
            int nb = buf ^ 1;
#pragma unroll
            for (int it = 0; it < 8; ++it) As[nb][tx][ty + 16 * it] = ar[it];
#pragma unroll
            for (int it = 0; it < 2; ++it) *(float4*)(&Bs[nb][kl0 + 8 * it][nl0]) = br[it];
            __syncthreads();
            buf = nb;
        }
    }
#pragma unroll
    for (int gi = 0; gi < 2; ++gi) {
#pragma unroll
        for (int r = 0; r < 4; ++r) {
            int m = m0 + gi * 64 + ty * 4 + r;
            if (m < VOCAB) {
                float* row = T + (size_t)m * TROW;
#pragma unroll
                for (int gc = 0; gc < 2; ++gc) {
                    int n = n0 + gc * 64 + tx * 4;
                    if (n < TROW) {
                        int a = gi * 4 + r, c = gc * 4;
                        *(float4*)(row + n) = make_float4(
                            acc[a][c], acc[a][c + 1], acc[a][c + 2], acc[a][c + 3]);
                    }
                }
            }
        }
    }
}

// XLA f32 tanh: the clamped rational approximation emitted by XLA's
// elemental_ir_emitter for f32 tanh (what jnp.tanh lowers to).
// Replaces (float)tanh((double)x): ~10 fma + 1 f32 div instead of an
// f64 libm chain -- the scan's per-step critical path shrinks ~3x.
__device__ __forceinline__ float tanh_xla(float x)
{
    const float kMax = 7.90531110763549805f;
    float xc = fminf(fmaxf(x, -kMax), kMax);
    float x2 = __fmul_rn(xc, xc);
    float np = fmaf(x2, -2.76076847742355e-16f, 2.00018790482477e-13f);
    np = fmaf(x2, np, -8.60467152213735e-11f);
    np = fmaf(x2, np,  5.12229709037114e-08f);
    np = fmaf(x2, np,  1.48572235717979e-05f);
    np = fmaf(x2, np,  6.37261928875436e-04f);
    np = fmaf(x2, np,  4.89352455891786e-03f);
    float num = __fmul_rn(xc, np);
    float dp = fmaf(x2, 1.19825839466702e-06f, 1.18534705686654e-04f);
    dp = fmaf(x2, dp, 2.26843463243900e-03f);
    dp = fmaf(x2, dp, 4.89352518554385e-03f);
    float r = num / dp;
    return (fabsf(x) < 0.0004f) ? x : r;
}

// ---------------- scan: frozen dot-product numerics, depth-3 prefetch, fast f32 tanh ----
__global__ __launch_bounds__(256, 1) void rnn_scan_np7(
    const int*   __restrict__ words,
    const float* __restrict__ T,
    const float* __restrict__ V,
    const float* __restrict__ bvec,
    const float* __restrict__ outW,
    const float* __restrict__ outB,
    float* __restrict__ out,
    int B)
{
    int tid = threadIdx.x;
    int g = tid >> 5, i = tid & 31;
    int b = blockIdx.x * 8 + g;
    bool act = (i < DD) && (b < B);
    int ii = (i < DD) ? i : (DD - 1);
    int bsafe = (b < B) ? b : 0;
    const int* wr = words + (size_t)bsafe * SEQ;

    float Vcol[DD];
#pragma unroll
    for (int j = 0; j < DD; ++j) Vcol[j] = V[j * DD + ii];
    float bi = bvec[ii];

    float hr[DD];
#pragma unroll
    for (int j = 0; j < DD; ++j) hr[j] = 0.f;
    hr[DD - 1] = 1.f;                // h0 = e_24

    bool sse = ((b & 3) == 0) && ((i & 3) == 0);
    const float* base = T + (size_t)ii * 28;

    float4 A0[7], A1[7], A2[7], A3[7];
    auto LD = [&](float4* dst, int t) {
        const float* R = base + (size_t)wr[t] * TROW;
#pragma unroll
        for (int u = 0; u < 7; ++u) dst[u] = *(const float4*)(R + u * 4);
    };

    float hnew = 0.f;
    auto STEP = [&](const float4* C) {
        float Tj[28];
#pragma unroll
        for (int u = 0; u < 7; ++u) {
            Tj[u * 4 + 0] = C[u].x; Tj[u * 4 + 1] = C[u].y;
            Tj[u * 4 + 2] = C[u].z; Tj[u * 4 + 3] = C[u].w;
        }
        float qv = Tj[25];
        float a;
        if (sse) {
            float p0 = 0.f, p1 = 0.f, p2 = 0.f, p3 = 0.f;
#pragma unroll
            for (int j = 0; j < 24; j += 4) {
                p0 = __fadd_rn(p0, __fmul_rn(Tj[j],     hr[j]));
                p1 = __fadd_rn(p1, __fmul_rn(Tj[j + 1], hr[j + 1]));
                p2 = __fadd_rn(p2, __fmul_rn(Tj[j + 2], hr[j + 2]));
                p3 = __fadd_rn(p3, __fmul_rn(Tj[j + 3], hr[j + 3]));
            }
            float s02 = __fadd_rn(p0, p2);
            float s13 = __fadd_rn(p1, p3);
            a = __fadd_rn(s02, s13);
            a = __fadd_rn(a, __fmul_rn(Tj[24], hr[24]));
        } else {
            a = 0.f;
#pragma unroll
            for (int j = 0; j < DD; ++j)
                a = __fadd_rn(a, __fmul_rn(Tj[j], hr[j]));
        }
        float r2 = 0.f;
#pragma unroll
        for (int j = 0; j < DD; ++j)
            r2 = fmaf(hr[j], Vcol[j], r2);
        float lin = __fadd_rn(__fadd_rn(qv, r2), bi);
        float pre = __fadd_rn(a, lin);
        hnew = act ? tanh_xla(pre) : 0.f;
#pragma unroll
        for (int j = 0; j < DD; ++j)
            hr[j] = __shfl(hnew, j, 32);
    };

    LD(A0, 0); LD(A1, 1); LD(A2, 2);
    int t = 0;
    for (; t + 6 < SEQ; t += 4) {            // t = 0,4,...,120
        LD(A3, t + 3); STEP(A0);
        LD(A0, t + 4); STEP(A1);
        LD(A1, t + 5); STEP(A2);
        LD(A2, t + 6); STEP(A3);
    }
    // t == 124: A0<-124, A1<-125, A2<-126 loaded; steps 124..127 remain
    LD(A3, 127);
    STEP(A0); STEP(A1); STEP(A2); STEP(A3);

    if (i < NC && b < B) {
        float acc = 0.f;
#pragma unroll
        for (int j = 0; j < DD; ++j)
            acc = fmaf(hr[j], outW[i * DD + j], acc);
        float l = __fadd_rn(acc, outB[i]);
        out[(size_t)b * NC + i] = (float)(1.0 / (1.0 + exp(-(double)l)));
    }
}

extern "C" void kernel_launch(void* const* d_in, const int* in_sizes, int n_in,
                              void* d_out, int out_size, void* d_ws, size_t ws_size,
                              hipStream_t stream)
{
    const int*   words = (const int*)d_in[0];
    const float* emb   = (const float*)d_in[2];
    const float* A     = (const float*)d_in[3];
    const float* W     = (const float*)d_in[4];
    const float* V     = (const float*)d_in[5];
    const float* bias  = (const float*)d_in[6];
    const float* outW  = (const float*)d_in[7];
    const float* outB  = (const float*)d_in[8];
    float* out = (float*)d_out;
    int B = in_sizes[0] / SEQ;

    const size_t T_OFF    = (size_t)1 << 20;                 // Bmat: 304*768*4 = 0.93 MB
    const size_t EMBT_OFF = (size_t)144 << 20;               // T: 50000*704*4 = 140.8 MB
    const size_t NEED     = EMBT_OFF + (size_t)KP * EMT * 4; // + embT 61 MB ≈ 205 MB
    float* Bmat = (float*)d_ws;
    float* T    = (float*)((char*)d_ws + T_OFF);
    float* embT = (float*)((char*)d_ws + EMBT_OFF);

    build_B<<<KP, 256, 0, stream>>>(A, W, Bmat);
    if (ws_size >= NEED) {
        transpose_emb<<<dim3(EMT / 64, (KP + 63) / 64), 256, 0, stream>>>(emb, embT);
        gemm_T3<<<dim3((VOCAB + 127) / 128, 3), 256, 0, stream>>>(embT, Bmat, T);
    } else {
        gemm_T<<<dim3((VOCAB + 127) / 128, 6), 256, 0, stream>>>(emb, Bmat, T);
    }
    rnn_scan_np7<<<(B + 7) / 8, 256, 0, stream>>>(words, T, V, bias, outW, outB, out, B);
}

// Round 7
// 493.033 us; speedup vs baseline: 2.9023x; 1.0028x over previous
//
#include <hip/hip_runtime.h>
#include <math.h>

#define VOCAB 50000
#define EE 301
#define KP 304     // padded K (multiple of 16; rows EE..KP-1 are zeros)
#define DD 25
#define SEQ 128
#define NC 5
#define BROW 768   // Bmat cols (scan-order, zero-padded): col i*28+j = A[i][e][j] (j<25), i*28+25 = W[e][i]
#define NUSE 700
#define TROW 704   // T row stride (floats); scan reads i*28 .. i*28+27
#define EMT 50112  // embT row stride (zero-padded cols VOCAB..EMT-1)

// async global->LDS DMA, 16B per lane, lane i lands at ldsbase + i*16
#define GLOAD_LDS16(g, l) __builtin_amdgcn_global_load_lds( \
    (const __attribute__((address_space(1))) void*)(g),     \
    (__attribute__((address_space(3))) void*)(l), 16, 0, 0)

// ---------------- Bmat[e][c'] in scan order; rows EE..KP-1 zero ----------------
__global__ __launch_bounds__(256) void build_B(
    const float* __restrict__ A, const float* __restrict__ W,
    float* __restrict__ Bmat)
{
    int e = blockIdx.x;
    for (int c = threadIdx.x; c < BROW; c += 256) {
        float v = 0.f;
        if (e < EE && c < NUSE) {
            int i = c / 28, j = c % 28;
            if (j < 25)       v = A[((size_t)i * EE + e) * DD + j];
            else if (j == 25) v = W[(size_t)e * DD + i];
        }
        Bmat[(size_t)e * BROW + c] = v;
    }
}

// ---------------- embT[k][m] = emb[m][k] (pure copy; zeros for k>=EE, m>=VOCAB) ----------------
__global__ __launch_bounds__(256) void transpose_emb(
    const float* __restrict__ emb, float* __restrict__ embT)
{
    __shared__ float t[64][65];
    int m0 = blockIdx.x * 64, k0 = blockIdx.y * 64;
    int tx = threadIdx.x & 63, ty = threadIdx.x >> 6;   // ty 0..3
#pragma unroll
    for (int it = 0; it < 16; ++it) {
        int m = m0 + ty * 16 + it;
        int k = k0 + tx;
        t[tx][ty * 16 + it] = (m < VOCAB && k < EE) ? emb[(size_t)m * EE + k] : 0.f;
    }
    __syncthreads();
#pragma unroll
    for (int it = 0; it < 16; ++it) {
        int kl = ty * 16 + it;
        int k = k0 + kl;
        if (k < KP) embT[(size_t)k * EMT + m0 + tx] = t[kl][tx];
    }
}

// ---------------- GEMM v3 (verbatim, bit-frozen): 128m x 256n, 8x16 microtile ----------
// ascending-k fmaf chain per element (k 0..303, zero tail).
__global__ __launch_bounds__(256, 1) void gemm_T3(
    const float* __restrict__ embT,  // [KP][EMT] k-major
    const float* __restrict__ Bmat,  // [KP][BROW]
    float* __restrict__ T)           // [VOCAB][TROW]
{
    __shared__ float As[2][16][128];   // 16 KB
    __shared__ float Bs[2][16][256];   // 32 KB
    int tid = threadIdx.x;
    int tx = tid & 15, ty = tid >> 4;
    int m0 = blockIdx.x * 128, n0 = blockIdx.y * 256;
    int wave = tid >> 6, lane = tid & 63;
    int krow = lane >> 5;
    int col4 = (lane & 31) * 4;

    float acc[8][16];
#pragma unroll
    for (int a = 0; a < 8; ++a)
#pragma unroll
        for (int c = 0; c < 16; ++c) acc[a][c] = 0.f;

    auto dma_tile = [&](int k0, int buf) {
#pragma unroll
        for (int j = 0; j < 2; ++j) {          // As: 2 instr/wave, 2 rows each
            int r0 = wave * 4 + j * 2;
            int k = k0 + r0 + krow;
            GLOAD_LDS16(embT + (size_t)k * EMT + m0 + col4, &As[buf][r0][0]);
        }
#pragma unroll
        for (int j = 0; j < 4; ++j) {          // Bs: 4 instr/wave, 1 row each
            int r = wave * 4 + j;
            int k = k0 + r;
            GLOAD_LDS16(Bmat + (size_t)k * BROW + n0 + lane * 4, &Bs[buf][r][0]);
        }
    };

    dma_tile(0, 0);
    __syncthreads();

    int buf = 0;
    for (int k0 = 0; k0 < KP; k0 += 16) {
        if (k0 + 16 < KP) dma_tile(k0 + 16, buf ^ 1);
#pragma unroll
        for (int kk = 0; kk < 16; ++kk) {      // global k strictly ascending
            float4 a0 = *(const float4*)&As[buf][kk][ty * 4];
            float4 a1 = *(const float4*)&As[buf][kk][64 + ty * 4];
            float4 b0 = *(const float4*)&Bs[buf][kk][tx * 4];
            float4 b1 = *(const float4*)&Bs[buf][kk][64 + tx * 4];
            float4 b2 = *(const float4*)&Bs[buf][kk][128 + tx * 4];
            float4 b3 = *(const float4*)&Bs[buf][kk][192 + tx * 4];
            float av[8]  = {a0.x, a0.y, a0.z, a0.w, a1.x, a1.y, a1.z, a1.w};
            float bv[16] = {b0.x, b0.y, b0.z, b0.w, b1.x, b1.y, b1.z, b1.w,
                            b2.x, b2.y, b2.z, b2.w, b3.x, b3.y, b3.z, b3.w};
#pragma unroll
            for (int a = 0; a < 8; ++a)
#pragma unroll
                for (int c = 0; c < 16; ++c)
                    acc[a][c] = fmaf(av[a], bv[c], acc[a][c]);
        }
        __syncthreads();
        buf ^= 1;
    }

    // epilogue: coalesced float4 stores (layout already scan-order)
#pragma unroll
    for (int gi = 0; gi < 2; ++gi) {
#pragma unroll
        for (int r = 0; r < 4; ++r) {
            int m = m0 + gi * 64 + ty * 4 + r;
            if (m < VOCAB) {
                float* row = T + (size_t)m * TROW;
#pragma unroll
                for (int gc = 0; gc < 4; ++gc) {
                    int n = n0 + gc * 64 + tx * 4;
                    if (n < TROW) {
                        int a = gi * 4 + r, c = gc * 4;
                        *(float4*)(row + n) = make_float4(
                            acc[a][c], acc[a][c + 1], acc[a][c + 2], acc[a][c + 3]);
                    }
                }
            }
        }
    }
}

// ---------------- fallback GEMM (R11): register-prefetch pipeline ----------------
__global__ __launch_bounds__(256, 2) void gemm_T(
    const float* __restrict__ emb, const float* __restrict__ Bmat,
    float* __restrict__ T)
{
    __shared__ float As[2][16][132];
    __shared__ float Bs[2][16][132];
    int tid = threadIdx.x;
    int tx = tid & 15, ty = tid >> 4;
    int m0 = blockIdx.x * 128, n0 = blockIdx.y * 128;
    float acc[8][8];
#pragma unroll
    for (int a = 0; a < 8; ++a)
#pragma unroll
        for (int c = 0; c < 8; ++c) acc[a][c] = 0.f;
    float ar[8]; float4 br[2];
    int kl0 = tid >> 5, nl0 = (tid & 31) * 4;
#pragma unroll
    for (int it = 0; it < 8; ++it) {
        int m = m0 + ty + 16 * it, k = tx;
        ar[it] = (m < VOCAB && k < EE) ? emb[(size_t)m * EE + k] : 0.f;
    }
#pragma unroll
    for (int it = 0; it < 2; ++it) {
        int k = kl0 + 8 * it;
        br[it] = (k < EE) ? *(const float4*)(Bmat + (size_t)k * BROW + n0 + nl0)
                          : make_float4(0.f, 0.f, 0.f, 0.f);
    }
#pragma unroll
    for (int it = 0; it < 8; ++it) As[0][tx][ty + 16 * it] = ar[it];
#pragma unroll
    for (int it = 0; it < 2; ++it) *(float4*)(&Bs[0][kl0 + 8 * it][nl0]) = br[it];
    __syncthreads();
    int buf = 0;
    for (int k0 = 0; k0 < EE; k0 += 16) {
        int k1 = k0 + 16;
        bool more = (k1 < EE);
        if (more) {
#pragma unroll
            for (int it = 0; it < 8; ++it) {
                int m = m0 + ty + 16 * it, k = k1 + tx;
                ar[it] = (m < VOCAB && k < EE) ? emb[(size_t)m * EE + k] : 0.f;
            }
#pragma unroll
            for (int it = 0; it < 2; ++it) {
                int k = k1 + kl0 + 8 * it;
                br[it] = (k < EE) ? *(const float4*)(Bmat + (size_t)k * BROW + n0 + nl0)
                                  : make_float4(0.f, 0.f, 0.f, 0.f);
            }
        }
#pragma unroll
        for (int kk = 0; kk < 16; ++kk) {
            float4 a0 = *(const float4*)&As[buf][kk][ty * 4];
            float4 a1 = *(const float4*)&As[buf][kk][64 + ty * 4];
            float4 b0 = *(const float4*)&Bs[buf][kk][tx * 4];
            float4 b1 = *(const float4*)&Bs[buf][kk][64 + tx * 4];
            float av[8] = {a0.x, a0.y, a0.z, a0.w, a1.x, a1.y, a1.z, a1.w};
            float bv[8] = {b0.x, b0.y, b0.z, b0.w, b1.x, b1.y, b1.z, b1.w};
#pragma unroll
            for (int a = 0; a < 8; ++a)
#pragma unroll
                for (int c = 0; c < 8; ++c)
                    acc[a][c] = fmaf(av[a], bv[c], acc[a][c]);
        }
        if (more) {
            int nb = buf ^ 1;
#pragma unroll
            for (int it = 0; it < 8; ++it) As[nb][tx][ty + 16 * it] = ar[it];
#pragma unroll
            for (int it = 0; it < 2; ++it) *(float4*)(&Bs[nb][kl0 + 8 * it][nl0]) = br[it];
            __syncthreads();
            buf = nb;
        }
    }
#pragma unroll
    for (int gi = 0; gi < 2; ++gi) {
#pragma unroll
        for (int r = 0; r < 4; ++r) {
            int m = m0 + gi * 64 + ty * 4 + r;
            if (m < VOCAB) {
                float* row = T + (size_t)m * TROW;
#pragma unroll
                for (int gc = 0; gc < 2; ++gc) {
                    int n = n0 + gc * 64 + tx * 4;
                    if (n < TROW) {
                        int a = gi * 4 + r, c = gc * 4;
                        *(float4*)(row + n) = make_float4(
                            acc[a][c], acc[a][c + 1], acc[a][c + 2], acc[a][c + 3]);
                    }
                }
            }
        }
    }
}

// XLA f32 tanh (kept from round 5: improved absmax to 0.0039)
__device__ __forceinline__ float tanh_xla(float x)
{
    const float kMax = 7.90531110763549805f;
    float xc = fminf(fmaxf(x, -kMax), kMax);
    float x2 = __fmul_rn(xc, xc);
    float np = fmaf(x2, -2.76076847742355e-16f, 2.00018790482477e-13f);
    np = fmaf(x2, np, -8.60467152213735e-11f);
    np = fmaf(x2, np,  5.12229709037114e-08f);
    np = fmaf(x2, np,  1.48572235717979e-05f);
    np = fmaf(x2, np,  6.37261928875436e-04f);
    np = fmaf(x2, np,  4.89352455891786e-03f);
    float num = __fmul_rn(xc, np);
    float dp = fmaf(x2, 1.19825839466702e-06f, 1.18534705686654e-04f);
    dp = fmaf(x2, dp, 2.26843463243900e-03f);
    dp = fmaf(x2, dp, 4.89352518554385e-03f);
    float r = num / dp;
    return (fabsf(x) < 0.0004f) ? x : r;
}

// ---------------- scan: r5 numerics (bit-identical), depth-5 prefetch (6 buffers) ----
// Only the load schedule changed vs the proven r5 kernel: loads are issued 5 steps
// ahead instead of 3, to cover the ~600-900cy random-row gather latency at the
// problem-fixed 4 waves/CU occupancy. STEP and all load values untouched.
__global__ __launch_bounds__(256, 1) void rnn_scan_np9(
    const int*   __restrict__ words,
    const float* __restrict__ T,
    const float* __restrict__ V,
    const float* __restrict__ bvec,
    const float* __restrict__ outW,
    const float* __restrict__ outB,
    float* __restrict__ out,
    int B)
{
    int tid = threadIdx.x;
    int g = tid >> 5, i = tid & 31;
    int b = blockIdx.x * 8 + g;
    bool act = (i < DD) && (b < B);
    int ii = (i < DD) ? i : (DD - 1);
    int bsafe = (b < B) ? b : 0;
    const int* wr = words + (size_t)bsafe * SEQ;

    float Vcol[DD];
#pragma unroll
    for (int j = 0; j < DD; ++j) Vcol[j] = V[j * DD + ii];
    float bi = bvec[ii];

    float hr[DD];
#pragma unroll
    for (int j = 0; j < DD; ++j) hr[j] = 0.f;
    hr[DD - 1] = 1.f;                // h0 = e_24

    bool sse = ((b & 3) == 0) && ((i & 3) == 0);
    const float* base = T + (size_t)ii * 28;

    float4 A0[7], A1[7], A2[7], A3[7], A4[7], A5[7];
    auto LD = [&](float4* dst, int t) {
        const float* R = base + (size_t)wr[t] * TROW;
#pragma unroll
        for (int u = 0; u < 7; ++u) dst[u] = *(const float4*)(R + u * 4);
    };

    float hnew = 0.f;
    auto STEP = [&](const float4* C) {
        float Tj[28];
#pragma unroll
        for (int u = 0; u < 7; ++u) {
            Tj[u * 4 + 0] = C[u].x; Tj[u * 4 + 1] = C[u].y;
            Tj[u * 4 + 2] = C[u].z; Tj[u * 4 + 3] = C[u].w;
        }
        float qv = Tj[25];
        float a;
        if (sse) {
            float p0 = 0.f, p1 = 0.f, p2 = 0.f, p3 = 0.f;
#pragma unroll
            for (int j = 0; j < 24; j += 4) {
                p0 = __fadd_rn(p0, __fmul_rn(Tj[j],     hr[j]));
                p1 = __fadd_rn(p1, __fmul_rn(Tj[j + 1], hr[j + 1]));
                p2 = __fadd_rn(p2, __fmul_rn(Tj[j + 2], hr[j + 2]));
                p3 = __fadd_rn(p3, __fmul_rn(Tj[j + 3], hr[j + 3]));
            }
            float s02 = __fadd_rn(p0, p2);
            float s13 = __fadd_rn(p1, p3);
            a = __fadd_rn(s02, s13);
            a = __fadd_rn(a, __fmul_rn(Tj[24], hr[24]));
        } else {
            a = 0.f;
#pragma unroll
            for (int j = 0; j < DD; ++j)
                a = __fadd_rn(a, __fmul_rn(Tj[j], hr[j]));
        }
        float r2 = 0.f;
#pragma unroll
        for (int j = 0; j < DD; ++j)
            r2 = fmaf(hr[j], Vcol[j], r2);
        float lin = __fadd_rn(__fadd_rn(qv, r2), bi);
        float pre = __fadd_rn(a, lin);
        hnew = act ? tanh_xla(pre) : 0.f;
#pragma unroll
        for (int j = 0; j < DD; ++j)
            hr[j] = __shfl(hnew, j, 32);
    };

    // depth-5 prefetch: 6 rotating buffers, loads issued 5 steps ahead
    LD(A0, 0); LD(A1, 1); LD(A2, 2); LD(A3, 3); LD(A4, 4);
    int t = 0;
    for (; t + 10 < SEQ; t += 6) {           // t = 0,6,...,114 (20 iters, steps 0..119)
        LD(A5, t + 5);  STEP(A0);
        LD(A0, t + 6);  STEP(A1);
        LD(A1, t + 7);  STEP(A2);
        LD(A2, t + 8);  STEP(A3);
        LD(A3, t + 9);  STEP(A4);
        LD(A4, t + 10); STEP(A5);
    }
    // after t=114 iter: A0=120, A1=121, A2=122, A3=123, A4=124; steps 120..127 remain
    LD(A5, 125); STEP(A0);                   // 120
    LD(A0, 126); STEP(A1);                   // 121
    LD(A1, 127); STEP(A2);                   // 122
    STEP(A3);                                // 123
    STEP(A4);                                // 124
    STEP(A5);                                // 125
    STEP(A0);                                // 126
    STEP(A1);                                // 127

    if (i < NC && b < B) {
        float acc = 0.f;
#pragma unroll
        for (int j = 0; j < DD; ++j)
            acc = fmaf(hr[j], outW[i * DD + j], acc);
        float l = __fadd_rn(acc, outB[i]);
        out[(size_t)b * NC + i] = (float)(1.0 / (1.0 + exp(-(double)l)));
    }
}

extern "C" void kernel_launch(void* const* d_in, const int* in_sizes, int n_in,
                              void* d_out, int out_size, void* d_ws, size_t ws_size,
                              hipStream_t stream)
{
    const int*   words = (const int*)d_in[0];
    const float* emb   = (const float*)d_in[2];
    const float* A     = (const float*)d_in[3];
    const float* W     = (const float*)d_in[4];
    const float* V     = (const float*)d_in[5];
    const float* bias  = (const float*)d_in[6];
    const float* outW  = (const float*)d_in[7];
    const float* outB  = (const float*)d_in[8];
    float* out = (float*)d_out;
    int B = in_sizes[0] / SEQ;

    const size_t T_OFF    = (size_t)1 << 20;                 // Bmat: 304*768*4 = 0.93 MB
    const size_t EMBT_OFF = (size_t)144 << 20;               // T: 50000*704*4 = 140.8 MB
    const size_t NEED     = EMBT_OFF + (size_t)KP * EMT * 4; // + embT 61 MB ≈ 205 MB
    float* Bmat = (float*)d_ws;
    float* T    = (float*)((char*)d_ws + T_OFF);
    float* embT = (float*)((char*)d_ws + EMBT_OFF);

    build_B<<<KP, 256, 0, stream>>>(A, W, Bmat);
    if (ws_size >= NEED) {
        transpose_emb<<<dim3(EMT / 64, (KP + 63) / 64), 256, 0, stream>>>(emb, embT);
        gemm_T3<<<dim3((VOCAB + 127) / 128, 3), 256, 0, stream>>>(embT, Bmat, T);
    } else {
        gemm_T<<<dim3((VOCAB + 127) / 128, 6), 256, 0, stream>>>(emb, Bmat, T);
    }
    rnn_scan_np9<<<(B + 7) / 8, 256, 0, stream>>>(words, T, V, bias, outW, outB, out, B);
}